// Round 27
// baseline (238.801 us; speedup 1.0000x reference)
//
#include <hip/hip_runtime.h>
#include <math.h>

#define DIM 768
#define NHEADS 12
#define HD 64
#define BATCH 4
#define NQ 1568            // 8*14*14  (T,H,W = 8,14,14)
#define NKV 392            // 8*7*7
#define LN_EPS 1e-6f

typedef unsigned short bfu;
typedef __attribute__((ext_vector_type(8))) short bf16x8;
typedef __attribute__((ext_vector_type(4))) float f32x4;

__device__ __forceinline__ float b2f(bfu u) {
    union { unsigned int i; float f; } v; v.i = ((unsigned int)u) << 16; return v.f;
}
__device__ __forceinline__ bfu f2b(float f) {
    union { float f; unsigned int i; } v; v.f = f;
    unsigned int r = v.i + 0x7FFFu + ((v.i >> 16) & 1u);
    return (bfu)(r >> 16);
}
// runtime-dtype load: fl==1 -> f32, fl==0 -> bf16, fl==2 -> zeros tensor
__device__ __forceinline__ float ldf(const void* p, size_t i, int fl) {
    if (fl == 1) return ((const float*)p)[i];
    if (fl == 0) return b2f(((const bfu*)p)[i]);
    return 0.f;
}

struct Ptrs { const void* p[16]; };

// ---- per-tensor dtype probe (verified working) ----------------------------
__global__ __launch_bounds__(64) void probe_kernel(Ptrs ptrs, int* __restrict__ flags) {
    const int cnts[16] = {4816896, 768, 768, 1769472, 2304, 589824, 768,
                          1728, 1728, 64, 64, 64, 64, 1728, 1728, 960};
    int i = blockIdx.x;
    const bfu* u = (const bfu*)ptrs.p[i];
    int S = cnts[i]; if (S > 1024) S = 1024;
    int nz = 0, outb = 0;
    for (int j = threadIdx.x; j < S; j += 64) {
        bfu v = u[j];
        if (v != 0) nz++;
        if ((j & 1) == 0) {
            int e = (v >> 7) & 0xFF;
            if (e < 96 || e > 134) outb++;
        }
    }
    #pragma unroll
    for (int o = 1; o < 64; o <<= 1) { nz += __shfl_xor(nz, o); outb += __shfl_xor(outb, o); }
    if (threadIdx.x == 0) {
        int ne = (S + 1) >> 1;
        flags[i] = (nz == 0) ? 2 : ((2 * outb > ne) ? 1 : 0);
    }
}

// ---- merged LayerNorm (blocks 0..6271) + qkv wcvt (blocks 6272..6703) -----
__global__ __launch_bounds__(256) void ln_wcvt_kernel(
    const void* __restrict__ x, const void* __restrict__ w,
    const void* __restrict__ b, bfu* __restrict__ xn,
    const void* __restrict__ qkvw, bfu* __restrict__ WT,
    const int* __restrict__ fl) {
    __shared__ float ss[4], ssq[4];
    __shared__ bfu tile[64][66];
    int t = threadIdx.x;
    if (blockIdx.x < 6272) {
        int fx = fl[0], fw = fl[1], fb = fl[2];
        int row = blockIdx.x;
        size_t base = (size_t)row * DIM;
        float v0 = ldf(x, base + t, fx);
        float v1 = ldf(x, base + t + 256, fx);
        float v2 = ldf(x, base + t + 512, fx);
        float s = v0 + v1 + v2;
        float sq = v0 * v0 + v1 * v1 + v2 * v2;
        #pragma unroll
        for (int o = 1; o < 64; o <<= 1) { s += __shfl_xor(s, o); sq += __shfl_xor(sq, o); }
        int wid = t >> 6;
        if ((t & 63) == 0) { ss[wid] = s; ssq[wid] = sq; }
        __syncthreads();
        s = ss[0] + ss[1] + ss[2] + ss[3];
        sq = ssq[0] + ssq[1] + ssq[2] + ssq[3];
        float mean = s * (1.0f / DIM);
        float var = sq * (1.0f / DIM) - mean * mean;
        float rs = rsqrtf(fmaxf(var, 0.0f) + LN_EPS);
        bfu* o = xn + base;
        o[t]       = f2b((v0 - mean) * rs * ldf(w, t, fw)       + ldf(b, t, fb));
        o[t + 256] = f2b((v1 - mean) * rs * ldf(w, t + 256, fw) + ldf(b, t + 256, fb));
        o[t + 512] = f2b((v2 - mean) * rs * ldf(w, t + 512, fw) + ldf(b, t + 512, fb));
    } else {
        int fw = fl[3];
        int bx = blockIdx.x - 6272;
        int c0 = (bx % 36) * 64;
        int k0 = (bx / 36) * 64;
        for (int id = t; id < 4096; id += 256) {
            int kk = id >> 6, cc = id & 63;
            tile[cc][kk] = f2b(ldf(qkvw, (size_t)(k0 + kk) * (3 * DIM) + c0 + cc, fw));
        }
        __syncthreads();
        for (int id = t; id < 4096; id += 256) {
            int cc = id >> 6, kk = id & 63;
            WT[(size_t)(c0 + cc) * 768 + k0 + kk] = tile[cc][kk];
        }
    }
}

// ---- weight transform (proj): WT[col][k] = bf16(W[k][col]) ----------------
__global__ __launch_bounds__(256) void wcvt_kernel(
    const void* __restrict__ W, bfu* __restrict__ WT,
    int ncols, const int* __restrict__ fl, int fwi) {
    int fw = fl[fwi];
    __shared__ bfu tile[64][66];
    int c0 = blockIdx.x * 64;
    int k0 = blockIdx.y * 64;
    int t = threadIdx.x;
    for (int id = t; id < 4096; id += 256) {
        int kk = id >> 6, cc = id & 63;
        tile[cc][kk] = f2b(ldf(W, (size_t)(k0 + kk) * ncols + c0 + cc, fw));
    }
    __syncthreads();
    for (int id = t; id < 4096; id += 256) {
        int cc = id >> 6, kk = id & 63;
        WT[(size_t)(c0 + cc) * 768 + k0 + kk] = tile[cc][kk];
    }
}

// ---- MFMA GEMM (1-wave, register-direct): C = A @ WT^T + bias(woff) ------
// 64x64 tile per 64-thread block; ldc-parameterized output (dual split for
// the 2-buffer kv case). Bijective XCD swizzle (ncol in 64-col units).
template<bool F32OUT>
__global__ __launch_bounds__(64) void gemm_mfma_kernel(
    const bfu* __restrict__ A, const bfu* __restrict__ WT,
    const void* __restrict__ bias, void* __restrict__ C0, void* __restrict__ C1,
    int woff, int split, int ncol, int ldc, const int* __restrict__ fl, int fbi) {
    int fb = fl[fbi];
    int l = threadIdx.x;
    int g = l >> 4, r = l & 15;

    int nwg = gridDim.x;
    int orig = blockIdx.x;
    int q = nwg >> 3, rem = nwg & 7;
    int xcd = orig & 7, idx = orig >> 3;
    int swz = ((xcd < rem) ? xcd * (q + 1) : rem * (q + 1) + (xcd - rem) * q) + idx;
    int brow = (swz / ncol) * 64;
    int bcol = (swz % ncol) * 64;

    f32x4 acc[4][4];
    #pragma unroll
    for (int m = 0; m < 4; ++m)
        #pragma unroll
        for (int n = 0; n < 4; ++n)
            #pragma unroll
            for (int q2 = 0; q2 < 4; ++q2) acc[m][n][q2] = 0.f;

    const bfu* arow[4];
    const bfu* wcol[4];
    #pragma unroll
    for (int m = 0; m < 4; ++m)
        arow[m] = A + (size_t)(brow + m * 16 + r) * 768 + g * 8;
    #pragma unroll
    for (int n = 0; n < 4; ++n)
        wcol[n] = WT + (size_t)(bcol + n * 16 + r) * 768 + g * 8;

    #pragma unroll 2
    for (int k0 = 0; k0 < DIM; k0 += 32) {
        bf16x8 afrag[4], bfrag[4];
        #pragma unroll
        for (int m = 0; m < 4; ++m) afrag[m] = *(const bf16x8*)(arow[m] + k0);
        #pragma unroll
        for (int n = 0; n < 4; ++n) bfrag[n] = *(const bf16x8*)(wcol[n] + k0);
        #pragma unroll
        for (int m = 0; m < 4; ++m)
            #pragma unroll
            for (int n = 0; n < 4; ++n)
                acc[m][n] = __builtin_amdgcn_mfma_f32_16x16x32_bf16(
                    afrag[m], bfrag[n], acc[m][n], 0, 0, 0);
    }

    bool second = (bcol >= split);
    int csub = second ? split : 0;
    float bv[4];
    #pragma unroll
    for (int n = 0; n < 4; ++n) bv[n] = ldf(bias, woff + bcol + n * 16 + r, fb);
    #pragma unroll
    for (int m = 0; m < 4; ++m) {
        #pragma unroll
        for (int n = 0; n < 4; ++n) {
            #pragma unroll
            for (int i = 0; i < 4; ++i) {
                float v = acc[m][n][i] + bv[n];
                size_t row = brow + m * 16 + g * 4 + i;
                size_t col = bcol + n * 16 + r - csub;
                if (F32OUT) {
                    ((float*)C0)[row * ldc + col] = v;
                } else {
                    bfu* Cb = second ? (bfu*)C1 : (bfu*)C0;
                    Cb[row * ldc + col] = f2b(v);
                }
            }
        }
    }
}

// ---- full-row depthwise conv3d pool + LN (stride-parameterized src) -------
__global__ __launch_bounds__(256) void pool3_kernel(
    const bfu* __restrict__ ksrc, const bfu* __restrict__ vsrc,
    const void* __restrict__ pwk, const void* __restrict__ pwv,
    const void* __restrict__ lwk, const void* __restrict__ lbk,
    const void* __restrict__ lwv, const void* __restrict__ lbv,
    bfu* __restrict__ kout, bfu* __restrict__ vout,
    int sstride, const int* __restrict__ fl) {
    int blk = blockIdx.x;
    bool isV = blk >= BATCH * NKV;
    int p = blk - (isV ? BATCH * NKV : 0);
    int b = p / NKV, kpos = p % NKV;
    const bfu* src = isV ? vsrc : ksrc;
    const void* pw = isV ? pwv : pwk;
    const void* lw = isV ? lwv : lwk;
    const void* lb = isV ? lbv : lbk;
    int fp = fl[isV ? 8 : 7], fw = fl[isV ? 11 : 9], fb = fl[isV ? 12 : 10];

    int t = threadIdx.x;
    int lane = t & 63, wv = t >> 6;
    int kt = kpos / 49;
    int r2 = kpos % 49;
    int kh = r2 / 7;
    int kw = r2 % 7;

    float wreg[27];
    #pragma unroll
    for (int tap = 0; tap < 27; ++tap)
        wreg[tap] = ldf(pw, (size_t)lane * 27 + tap, fp);

    float acc0 = 0.f, acc1 = 0.f, acc2 = 0.f;
    #pragma unroll
    for (int dt = 0; dt < 3; ++dt) {
        int tt = kt + dt - 1;
        if (tt < 0 || tt >= 8) continue;
        #pragma unroll
        for (int dh = 0; dh < 3; ++dh) {
            int hh = kh * 2 + dh - 1;
            if (hh < 0 || hh >= 14) continue;
            #pragma unroll
            for (int dw = 0; dw < 3; ++dw) {
                int ww = kw * 2 + dw - 1;
                if (ww < 0 || ww >= 14) continue;
                int n = (tt * 14 + hh) * 14 + ww;
                const bfu* row = src + (size_t)(b * NQ + n) * sstride + t;
                float wg = wreg[dt * 9 + dh * 3 + dw];
                acc0 += b2f(row[0])   * wg;
                acc1 += b2f(row[256]) * wg;
                acc2 += b2f(row[512]) * wg;
            }
        }
    }

    float lww = ldf(lw, lane, fw), lbb = ldf(lb, lane, fb);
    float accs[3] = {acc0, acc1, acc2};
    #pragma unroll
    for (int k = 0; k < 3; ++k) {
        float a = accs[k];
        float s = a, sq = a * a;
        #pragma unroll
        for (int o = 1; o < 64; o <<= 1) { s += __shfl_xor(s, o); sq += __shfl_xor(sq, o); }
        float mean = s * (1.0f / 64.0f);
        float var = sq * (1.0f / 64.0f) - mean * mean;
        float rs = rsqrtf(fmaxf(var, 0.0f) + LN_EPS);
        float v = (a - mean) * rs * lww + lbb;
        int h = 4 * k + wv;
        if (isV) vout[((size_t)(b * NHEADS + h) * HD + lane) * NKV + kpos] = f2b(v);
        else     kout[((size_t)(b * NHEADS + h) * NKV + kpos) * HD + lane] = f2b(v);
    }
}

// ---- MFMA flash attention: 4 waves x 16 q-rows, kv tiles of 32 ------------
// Fragment-order LDS tiles; bf16 bias tables; q-source stride parameterized.
__global__ __launch_bounds__(256) void attn_mfma_kernel(
    const bfu* __restrict__ qb, const bfu* __restrict__ kp,
    const bfu* __restrict__ vt, const void* __restrict__ rpt,
    const void* __restrict__ rph, const void* __restrict__ rpw,
    bfu* __restrict__ ao, int qs, const int* __restrict__ fl) {
    int fh = fl[13], fwF = fl[14], ft = fl[15];
    __shared__ __align__(16) unsigned char smem[20992];
    bfu   (*bsHWb)[52] = reinterpret_cast<bfu(*)[52]>(smem);
    bfu*  Pl           = reinterpret_cast<bfu*>(smem + 6656);
    bfu*  Kl           = reinterpret_cast<bfu*>(smem + 10752);
    bfu*  Vl           = reinterpret_cast<bfu*>(smem + 14848);
    float (*bsT)[8]    = reinterpret_cast<float(*)[8]>(smem + 18944);
    bfu   (*Rlb)[68]   = reinterpret_cast<bfu(*)[68]>(smem);
    float (*bsD)[14]   = reinterpret_cast<float(*)[14]>(smem + 10752);

    int t = threadIdx.x;
    int l = t & 63, w = t >> 6;
    int g = l >> 4, r = l & 15;
    int blk = blockIdx.x;
    int qt = blk % 25, bh = blk / 25;
    int h = bh % NHEADS, b = bh / NHEADS;
    int rowbase = qt * 64;
    int qw = rowbase + w * 16;
    int qwc = (qw < NQ) ? qw : (NQ - 16);

    for (int id = t; id < 69 * 64; id += 256) {
        int j = id >> 6, c = id & 63;
        const void* R; int row, rfl;
        if (j < 15)      { R = rpt; row = j;      rfl = ft; }
        else if (j < 42) { R = rph; row = j - 15; rfl = fh; }
        else             { R = rpw; row = j - 42; rfl = fwF; }
        Rlb[j][c] = f2b(ldf(R, (size_t)row * HD + c, rfl));
    }
    int rr = t >> 2, sub = t & 3;
    int nqr = rowbase + rr;
    int nqc = (nqr < NQ) ? nqr : (NQ - 1);
    float qv16[16];
    {
        const bfu* qrow = qb + (size_t)(b * NQ + nqc) * qs + h * HD + sub * 16;
        #pragma unroll
        for (int c4 = 0; c4 < 4; ++c4) {
            ushort4 u = *(const ushort4*)(qrow + c4 * 4);
            qv16[c4 * 4 + 0] = b2f(u.x);
            qv16[c4 * 4 + 1] = b2f(u.y);
            qv16[c4 * 4 + 2] = b2f(u.z);
            qv16[c4 * 4 + 3] = b2f(u.w);
        }
    }
    __syncthreads();

    {
        int tq = nqc / 196, hq = (nqc % 196) / 14, wq = nqc % 14;
        #pragma unroll
        for (int idx = 0; idx < 22; ++idx) {
            int j;
            if (idx < 8)       j = tq - idx + 7;
            else if (idx < 15) j = 15 + hq - 2 * (idx - 8) + 12;
            else               j = 42 + wq - 2 * (idx - 15) + 12;
            float part = 0.f;
            #pragma unroll
            for (int c4 = 0; c4 < 4; ++c4) {
                ushort4 u = *(const ushort4*)&Rlb[j][sub * 16 + c4 * 4];
                part += qv16[c4 * 4 + 0] * b2f(u.x) + qv16[c4 * 4 + 1] * b2f(u.y)
                      + qv16[c4 * 4 + 2] * b2f(u.z) + qv16[c4 * 4 + 3] * b2f(u.w);
            }
            part += __shfl_xor(part, 1);
            part += __shfl_xor(part, 2);
            if (sub == 0) {
                if (idx < 8) bsT[rr][idx] = part - 8.0f;
                else         bsD[rr][idx - 8] = part;
            }
        }
    }
    __syncthreads();

    for (int id = t; id < 64 * 49; id += 256) {
        int rrj = id / 49, r2 = id - rrj * 49;
        bsHWb[rrj][r2] = f2b(bsD[rrj][r2 / 7] + bsD[rrj][7 + r2 % 7]);
    }

    size_t qgrow = (size_t)(b * NQ + qwc + r) * qs + h * HD;
    bf16x8 aq0 = *(const bf16x8*)(qb + qgrow + g * 8);
    bf16x8 aq1 = *(const bf16x8*)(qb + qgrow + 32 + g * 8);

    f32x4 o0, o1, o2, o3;
    #pragma unroll
    for (int i = 0; i < 4; ++i) { o0[i] = 0.f; o1[i] = 0.f; o2[i] = 0.f; o3[i] = 0.f; }
    float lrp[4] = {0.f, 0.f, 0.f, 0.f};

    const bfu* kbase = kp + (size_t)bh * NKV * HD;
    const bfu* vbase = vt + (size_t)bh * HD * NKV;
    f32x4 zero;
    #pragma unroll
    for (int i = 0; i < 4; ++i) zero[i] = 0.f;

    const bfu* ksrc0 = kbase + (size_t)((t >> 7) * 16 + (t & 15)) * HD + ((t >> 4) & 7) * 8;
    const bfu* vsrc0 = vbase + (size_t)((t >> 6) * 16 + (t & 15)) * NKV + ((t >> 4) & 3) * 8;
    int lslot = t * 8;

    int myrow = w * 512 + ((r >> 3) * 16) * 8 + (r & 7);
    int myrow1 = w * 512 + ((2 + (r >> 3)) * 16) * 8 + (r & 7);

    for (int kt0 = 0; kt0 < NKV; kt0 += 32) {
        __syncthreads();
        *(bf16x8*)&Kl[lslot] = *(const bf16x8*)(ksrc0 + (size_t)kt0 * HD);
        *(bf16x8*)&Vl[lslot] = *(const bf16x8*)(vsrc0 + kt0);
        __syncthreads();

        f32x4 s0 = zero, s1 = zero;
        {
            int sl = (g * 16 + r) * 8;
            bf16x8 kf;
            kf = *(const bf16x8*)&Kl[sl];
            s0 = __builtin_amdgcn_mfma_f32_16x16x32_bf16(aq0, kf, s0, 0, 0, 0);
            kf = *(const bf16x8*)&Kl[512 + sl];
            s0 = __builtin_amdgcn_mfma_f32_16x16x32_bf16(aq1, kf, s0, 0, 0, 0);
            kf = *(const bf16x8*)&Kl[1024 + sl];
            s1 = __builtin_amdgcn_mfma_f32_16x16x32_bf16(aq0, kf, s1, 0, 0, 0);
            kf = *(const bf16x8*)&Kl[1536 + sl];
            s1 = __builtin_amdgcn_mfma_f32_16x16x32_bf16(aq1, kf, s1, 0, 0, 0);
        }
        int kj0 = kt0 + r, kj1 = kt0 + 16 + r;
        bool msk0 = (kj0 >= NKV);
        bool msk1 = (kj1 >= NKV);
        int kj0c = msk0 ? (NKV - 1) : kj0;
        int kj1c = msk1 ? (NKV - 1) : kj1;
        int kt_0 = kj0c / 49, r2_0 = kj0c - kt_0 * 49;
        int kt_1 = kj1c / 49, r2_1 = kj1c - kt_1 * 49;
        #pragma unroll
        for (int i = 0; i < 4; ++i) {
            int br = w * 16 + 4 * g + i;
            float v0 = s0[i] * 0.125f + bsT[br][kt_0] + b2f(bsHWb[br][r2_0]);
            float v1 = s1[i] * 0.125f + bsT[br][kt_1] + b2f(bsHWb[br][r2_1]);
            float p0 = msk0 ? 0.f : __expf(v0);
            float p1 = msk1 ? 0.f : __expf(v1);
            lrp[i] += p0 + p1;
            s0[i] = p0; s1[i] = p1;
        }
        #pragma unroll
        for (int i = 0; i < 4; ++i) {
            Pl[myrow + (4 * g + i) * 8]  = f2b(s0[i]);
            Pl[myrow1 + (4 * g + i) * 8] = f2b(s1[i]);
        }
        bf16x8 pf = *(const bf16x8*)&Pl[w * 512 + (g * 16 + r) * 8];
        int vsl = (g * 16 + r) * 8;
        bf16x8 vf;
        vf = *(const bf16x8*)&Vl[vsl];
        o0 = __builtin_amdgcn_mfma_f32_16x16x32_bf16(pf, vf, o0, 0, 0, 0);
        vf = *(const bf16x8*)&Vl[512 + vsl];
        o1 = __builtin_amdgcn_mfma_f32_16x16x32_bf16(pf, vf, o1, 0, 0, 0);
        vf = *(const bf16x8*)&Vl[1024 + vsl];
        o2 = __builtin_amdgcn_mfma_f32_16x16x32_bf16(pf, vf, o2, 0, 0, 0);
        vf = *(const bf16x8*)&Vl[1536 + vsl];
        o3 = __builtin_amdgcn_mfma_f32_16x16x32_bf16(pf, vf, o3, 0, 0, 0);
    }

    if (qw < NQ) {
        #pragma unroll
        for (int i = 0; i < 4; ++i) {
            float lsum = lrp[i];
            lsum += __shfl_xor(lsum, 1);
            lsum += __shfl_xor(lsum, 2);
            lsum += __shfl_xor(lsum, 4);
            lsum += __shfl_xor(lsum, 8);
            float inv = 1.f / lsum;
            size_t rix = (size_t)(b * NQ + qw + 4 * g + i);
            size_t qres = rix * qs + h * HD + r;
            size_t orow = rix * DIM + h * HD + r;
            ao[orow]      = f2b(o0[i] * inv + b2f(qb[qres]));
            ao[orow + 16] = f2b(o1[i] * inv + b2f(qb[qres + 16]));
            ao[orow + 32] = f2b(o2[i] * inv + b2f(qb[qres + 32]));
            ao[orow + 48] = f2b(o3[i] * inv + b2f(qb[qres + 48]));
        }
    }
}

extern "C" void kernel_launch(void* const* d_in, const int* in_sizes, int n_in,
                              void* d_out, int out_size, void* d_ws, size_t ws_size,
                              hipStream_t stream) {
    Ptrs ptrs;
    for (int i = 0; i < 16; ++i) ptrs.p[i] = d_in[i];
    const void* x      = d_in[0];
    const void* ln_w   = d_in[1];
    const void* ln_b   = d_in[2];
    const void* qkv_w  = d_in[3];
    const void* qkv_b  = d_in[4];
    const void* proj_w = d_in[5];
    const void* proj_b = d_in[6];
    const void* poolk_w = d_in[7];
    const void* poolv_w = d_in[8];
    const void* rph    = d_in[13];
    const void* rpw    = d_in[14];
    const void* rpt    = d_in[15];

    bfu* ws = (bfu*)d_ws;
    float* out = (float*)d_out;
    bfu* WTq = (bfu*)d_out;               // 1,769,472 elems, dead before proj

    if (ws_size >= 43352192ULL) {
        // ---------- layout B: fused QKV (single GEMM, A read once) ----------
        bfu* A   = ws;                    //  4,816,896: xn, later attention out
        bfu* QKV = ws + 4816896;          // 14,450,688: fused [6272][2304]
        bfu* kp  = ws + 19267584;         //  1,204,224: K [bh][kj][d]; later WTp
        bfu* vt  = ws + 20471808;         //  1,204,224: V^T [bh][d][kj]
        int* flags = (int*)(ws + 21676032);

        probe_kernel<<<16, 64, 0, stream>>>(ptrs, flags);
        ln_wcvt_kernel<<<6704, 256, 0, stream>>>(x, ln_w, ln_b, A, qkv_w, WTq, flags);

        // fused QKV GEMM: N=2304, ldc=2304, 98x36 = 3528 blocks
        gemm_mfma_kernel<false><<<98 * 36, 64, 0, stream>>>(
            A, WTq, qkv_b, QKV, nullptr, 0, 1 << 30, 36, 2304, flags, 4);

        // pools read k (col 768) / v (col 1536) from fused QKV, stride 2304
        pool3_kernel<<<2 * BATCH * NKV, 256, 0, stream>>>(
            QKV + 768, QKV + 1536, poolk_w, poolv_w,
            d_in[9], d_in[10], d_in[11], d_in[12], kp, vt, 2304, flags);

        // attention: q from QKV (stride 2304, col 0) -> ao in A (stride 768)
        attn_mfma_kernel<<<48 * 25, 256, 0, stream>>>(
            QKV, kp, vt, rpt, rph, rpw, A, 2304, flags);

        // proj_w -> bf16 W^T into kp region (dead after attn)
        wcvt_kernel<<<dim3(12, 12), 256, 0, stream>>>(proj_w, kp, DIM, flags, 5);

        gemm_mfma_kernel<true><<<98 * 12, 64, 0, stream>>>(
            A, kp, proj_b, out, nullptr, 0, 1 << 30, 12, 768, flags, 6);
    } else {
        // ---------- layout A: round-26 certified path (24.08 MB floor) ------
        bfu* A  = ws;                       // 4,816,896: xn, later attention out
        bfu* Bf = ws + 4816896;             // 4,816,896: v-slice, then q-slice
        bfu* kp = ws + 9633792;             // 1,204,224: K; later WT_proj
        bfu* vt = ws + 10838016;            // 1,204,224: V^T
        int* flags = (int*)(ws + 12042240);
        bfu* kslice = (bfu*)d_out + 1769472;// 4,816,896: k projection (d_out)

        probe_kernel<<<16, 64, 0, stream>>>(ptrs, flags);
        ln_wcvt_kernel<<<6704, 256, 0, stream>>>(x, ln_w, ln_b, A, qkv_w, WTq, flags);

        gemm_mfma_kernel<false><<<98 * 24, 64, 0, stream>>>(
            A, WTq + (size_t)DIM * 768, qkv_b, kslice, Bf, DIM, DIM, 24, 768, flags, 4);

        pool3_kernel<<<2 * BATCH * NKV, 256, 0, stream>>>(
            kslice, Bf, poolk_w, poolv_w,
            d_in[9], d_in[10], d_in[11], d_in[12], kp, vt, 768, flags);

        gemm_mfma_kernel<false><<<98 * 12, 64, 0, stream>>>(
            A, WTq, qkv_b, Bf, nullptr, 0, 1 << 30, 12, 768, flags, 4);

        attn_mfma_kernel<<<48 * 25, 256, 0, stream>>>(
            Bf, kp, vt, rpt, rph, rpw, A, 768, flags);

        wcvt_kernel<<<dim3(12, 12), 256, 0, stream>>>(proj_w, kp, DIM, flags, 5);

        gemm_mfma_kernel<true><<<98 * 12, 64, 0, stream>>>(
            A, kp, proj_b, out, nullptr, 0, 1 << 30, 12, 768, flags, 6);
    }
}

// Round 28
// 233.208 us; speedup vs baseline: 1.0240x; 1.0240x over previous
//
#include <hip/hip_runtime.h>
#include <math.h>

#define DIM 768
#define NHEADS 12
#define HD 64
#define BATCH 4
#define NQ 1568            // 8*14*14  (T,H,W = 8,14,14)
#define NKV 392            // 8*7*7
#define LN_EPS 1e-6f

typedef unsigned short bfu;
typedef __attribute__((ext_vector_type(8))) short bf16x8;
typedef __attribute__((ext_vector_type(4))) float f32x4;

__device__ __forceinline__ float b2f(bfu u) {
    union { unsigned int i; float f; } v; v.i = ((unsigned int)u) << 16; return v.f;
}
__device__ __forceinline__ bfu f2b(float f) {
    union { float f; unsigned int i; } v; v.f = f;
    unsigned int r = v.i + 0x7FFFu + ((v.i >> 16) & 1u);
    return (bfu)(r >> 16);
}
// runtime-dtype load: fl==1 -> f32, fl==0 -> bf16, fl==2 -> zeros tensor
__device__ __forceinline__ float ldf(const void* p, size_t i, int fl) {
    if (fl == 1) return ((const float*)p)[i];
    if (fl == 0) return b2f(((const bfu*)p)[i]);
    return 0.f;
}

struct Ptrs { const void* p[16]; };

// ---- per-tensor dtype probe (verified working) ----------------------------
__global__ __launch_bounds__(64) void probe_kernel(Ptrs ptrs, int* __restrict__ flags) {
    const int cnts[16] = {4816896, 768, 768, 1769472, 2304, 589824, 768,
                          1728, 1728, 64, 64, 64, 64, 1728, 1728, 960};
    int i = blockIdx.x;
    const bfu* u = (const bfu*)ptrs.p[i];
    int S = cnts[i]; if (S > 1024) S = 1024;
    int nz = 0, outb = 0;
    for (int j = threadIdx.x; j < S; j += 64) {
        bfu v = u[j];
        if (v != 0) nz++;
        if ((j & 1) == 0) {
            int e = (v >> 7) & 0xFF;
            if (e < 96 || e > 134) outb++;
        }
    }
    #pragma unroll
    for (int o = 1; o < 64; o <<= 1) { nz += __shfl_xor(nz, o); outb += __shfl_xor(outb, o); }
    if (threadIdx.x == 0) {
        int ne = (S + 1) >> 1;
        flags[i] = (nz == 0) ? 2 : ((2 * outb > ne) ? 1 : 0);
    }
}

// ---- merged LayerNorm (0..6271) + qkv wcvt (6272..6703) + proj wcvt -------
__global__ __launch_bounds__(256) void ln_wcvt_kernel(
    const void* __restrict__ x, const void* __restrict__ w,
    const void* __restrict__ b, bfu* __restrict__ xn,
    const void* __restrict__ qkvw, bfu* __restrict__ WT,
    const void* __restrict__ projw, bfu* __restrict__ WTp,
    const int* __restrict__ fl) {
    __shared__ float ss[4], ssq[4];
    __shared__ bfu tile[64][66];
    int t = threadIdx.x;
    if (blockIdx.x < 6272) {
        int fx = fl[0], fw = fl[1], fb = fl[2];
        int row = blockIdx.x;
        size_t base = (size_t)row * DIM;
        float v0 = ldf(x, base + t, fx);
        float v1 = ldf(x, base + t + 256, fx);
        float v2 = ldf(x, base + t + 512, fx);
        float s = v0 + v1 + v2;
        float sq = v0 * v0 + v1 * v1 + v2 * v2;
        #pragma unroll
        for (int o = 1; o < 64; o <<= 1) { s += __shfl_xor(s, o); sq += __shfl_xor(sq, o); }
        int wid = t >> 6;
        if ((t & 63) == 0) { ss[wid] = s; ssq[wid] = sq; }
        __syncthreads();
        s = ss[0] + ss[1] + ss[2] + ss[3];
        sq = ssq[0] + ssq[1] + ssq[2] + ssq[3];
        float mean = s * (1.0f / DIM);
        float var = sq * (1.0f / DIM) - mean * mean;
        float rs = rsqrtf(fmaxf(var, 0.0f) + LN_EPS);
        bfu* o = xn + base;
        o[t]       = f2b((v0 - mean) * rs * ldf(w, t, fw)       + ldf(b, t, fb));
        o[t + 256] = f2b((v1 - mean) * rs * ldf(w, t + 256, fw) + ldf(b, t + 256, fb));
        o[t + 512] = f2b((v2 - mean) * rs * ldf(w, t + 512, fw) + ldf(b, t + 512, fb));
    } else if (blockIdx.x < 6704) {
        int fw = fl[3];
        int bx = blockIdx.x - 6272;
        int c0 = (bx % 36) * 64;
        int k0 = (bx / 36) * 64;
        for (int id = t; id < 4096; id += 256) {
            int kk = id >> 6, cc = id & 63;
            tile[cc][kk] = f2b(ldf(qkvw, (size_t)(k0 + kk) * (3 * DIM) + c0 + cc, fw));
        }
        __syncthreads();
        for (int id = t; id < 4096; id += 256) {
            int cc = id >> 6, kk = id & 63;
            WT[(size_t)(c0 + cc) * 768 + k0 + kk] = tile[cc][kk];
        }
    } else {
        int fw = fl[5];
        int bx = blockIdx.x - 6704;       // 144 blocks: proj_w 768x768
        int c0 = (bx % 12) * 64;
        int k0 = (bx / 12) * 64;
        for (int id = t; id < 4096; id += 256) {
            int kk = id >> 6, cc = id & 63;
            tile[cc][kk] = f2b(ldf(projw, (size_t)(k0 + kk) * DIM + c0 + cc, fw));
        }
        __syncthreads();
        for (int id = t; id < 4096; id += 256) {
            int cc = id >> 6, kk = id & 63;
            WTp[(size_t)(c0 + cc) * 768 + k0 + kk] = tile[cc][kk];
        }
    }
}

// ---- MFMA GEMM (1-wave, register-direct): C = A @ WT^T + bias(woff) ------
// 64x64 tile per 64-thread block; ldc-parameterized output (dual split for
// the 2-buffer kv case). Bijective XCD swizzle (ncol in 64-col units).
template<bool F32OUT>
__global__ __launch_bounds__(64) void gemm_mfma_kernel(
    const bfu* __restrict__ A, const bfu* __restrict__ WT,
    const void* __restrict__ bias, void* __restrict__ C0, void* __restrict__ C1,
    int woff, int split, int ncol, int ldc, const int* __restrict__ fl, int fbi) {
    int fb = fl[fbi];
    int l = threadIdx.x;
    int g = l >> 4, r = l & 15;

    int nwg = gridDim.x;
    int orig = blockIdx.x;
    int q = nwg >> 3, rem = nwg & 7;
    int xcd = orig & 7, idx = orig >> 3;
    int swz = ((xcd < rem) ? xcd * (q + 1) : rem * (q + 1) + (xcd - rem) * q) + idx;
    int brow = (swz / ncol) * 64;
    int bcol = (swz % ncol) * 64;

    f32x4 acc[4][4];
    #pragma unroll
    for (int m = 0; m < 4; ++m)
        #pragma unroll
        for (int n = 0; n < 4; ++n)
            #pragma unroll
            for (int q2 = 0; q2 < 4; ++q2) acc[m][n][q2] = 0.f;

    const bfu* arow[4];
    const bfu* wcol[4];
    #pragma unroll
    for (int m = 0; m < 4; ++m)
        arow[m] = A + (size_t)(brow + m * 16 + r) * 768 + g * 8;
    #pragma unroll
    for (int n = 0; n < 4; ++n)
        wcol[n] = WT + (size_t)(bcol + n * 16 + r) * 768 + g * 8;

    #pragma unroll 2
    for (int k0 = 0; k0 < DIM; k0 += 32) {
        bf16x8 afrag[4], bfrag[4];
        #pragma unroll
        for (int m = 0; m < 4; ++m) afrag[m] = *(const bf16x8*)(arow[m] + k0);
        #pragma unroll
        for (int n = 0; n < 4; ++n) bfrag[n] = *(const bf16x8*)(wcol[n] + k0);
        #pragma unroll
        for (int m = 0; m < 4; ++m)
            #pragma unroll
            for (int n = 0; n < 4; ++n)
                acc[m][n] = __builtin_amdgcn_mfma_f32_16x16x32_bf16(
                    afrag[m], bfrag[n], acc[m][n], 0, 0, 0);
    }

    bool second = (bcol >= split);
    int csub = second ? split : 0;
    float bv[4];
    #pragma unroll
    for (int n = 0; n < 4; ++n) bv[n] = ldf(bias, woff + bcol + n * 16 + r, fb);
    #pragma unroll
    for (int m = 0; m < 4; ++m) {
        #pragma unroll
        for (int n = 0; n < 4; ++n) {
            #pragma unroll
            for (int i = 0; i < 4; ++i) {
                float v = acc[m][n][i] + bv[n];
                size_t row = brow + m * 16 + g * 4 + i;
                size_t col = bcol + n * 16 + r - csub;
                if (F32OUT) {
                    ((float*)C0)[row * ldc + col] = v;
                } else {
                    bfu* Cb = second ? (bfu*)C1 : (bfu*)C0;
                    Cb[row * ldc + col] = f2b(v);
                }
            }
        }
    }
}

// ---- full-row depthwise conv3d pool + LN (stride-parameterized src) -------
__global__ __launch_bounds__(256) void pool3_kernel(
    const bfu* __restrict__ ksrc, const bfu* __restrict__ vsrc,
    const void* __restrict__ pwk, const void* __restrict__ pwv,
    const void* __restrict__ lwk, const void* __restrict__ lbk,
    const void* __restrict__ lwv, const void* __restrict__ lbv,
    bfu* __restrict__ kout, bfu* __restrict__ vout,
    int sstride, const int* __restrict__ fl) {
    int blk = blockIdx.x;
    bool isV = blk >= BATCH * NKV;
    int p = blk - (isV ? BATCH * NKV : 0);
    int b = p / NKV, kpos = p % NKV;
    const bfu* src = isV ? vsrc : ksrc;
    const void* pw = isV ? pwv : pwk;
    const void* lw = isV ? lwv : lwk;
    const void* lb = isV ? lbv : lbk;
    int fp = fl[isV ? 8 : 7], fw = fl[isV ? 11 : 9], fb = fl[isV ? 12 : 10];

    int t = threadIdx.x;
    int lane = t & 63, wv = t >> 6;
    int kt = kpos / 49;
    int r2 = kpos % 49;
    int kh = r2 / 7;
    int kw = r2 % 7;

    float wreg[27];
    #pragma unroll
    for (int tap = 0; tap < 27; ++tap)
        wreg[tap] = ldf(pw, (size_t)lane * 27 + tap, fp);

    float acc0 = 0.f, acc1 = 0.f, acc2 = 0.f;
    #pragma unroll
    for (int dt = 0; dt < 3; ++dt) {
        int tt = kt + dt - 1;
        if (tt < 0 || tt >= 8) continue;
        #pragma unroll
        for (int dh = 0; dh < 3; ++dh) {
            int hh = kh * 2 + dh - 1;
            if (hh < 0 || hh >= 14) continue;
            #pragma unroll
            for (int dw = 0; dw < 3; ++dw) {
                int ww = kw * 2 + dw - 1;
                if (ww < 0 || ww >= 14) continue;
                int n = (tt * 14 + hh) * 14 + ww;
                const bfu* row = src + (size_t)(b * NQ + n) * sstride + t;
                float wg = wreg[dt * 9 + dh * 3 + dw];
                acc0 += b2f(row[0])   * wg;
                acc1 += b2f(row[256]) * wg;
                acc2 += b2f(row[512]) * wg;
            }
        }
    }

    float lww = ldf(lw, lane, fw), lbb = ldf(lb, lane, fb);
    float accs[3] = {acc0, acc1, acc2};
    #pragma unroll
    for (int k = 0; k < 3; ++k) {
        float a = accs[k];
        float s = a, sq = a * a;
        #pragma unroll
        for (int o = 1; o < 64; o <<= 1) { s += __shfl_xor(s, o); sq += __shfl_xor(sq, o); }
        float mean = s * (1.0f / 64.0f);
        float var = sq * (1.0f / 64.0f) - mean * mean;
        float rs = rsqrtf(fmaxf(var, 0.0f) + LN_EPS);
        float v = (a - mean) * rs * lww + lbb;
        int h = 4 * k + wv;
        if (isV) vout[((size_t)(b * NHEADS + h) * HD + lane) * NKV + kpos] = f2b(v);
        else     kout[((size_t)(b * NHEADS + h) * NKV + kpos) * HD + lane] = f2b(v);
    }
}

// ---- MFMA flash attention: 4 waves x 16 q-rows, kv tiles of 32 ------------
// Fragment-order LDS tiles; bf16 bias tables; q-source stride parameterized.
__global__ __launch_bounds__(256) void attn_mfma_kernel(
    const bfu* __restrict__ qb, const bfu* __restrict__ kp,
    const bfu* __restrict__ vt, const void* __restrict__ rpt,
    const void* __restrict__ rph, const void* __restrict__ rpw,
    bfu* __restrict__ ao, int qs, const int* __restrict__ fl) {
    int fh = fl[13], fwF = fl[14], ft = fl[15];
    __shared__ __align__(16) unsigned char smem[20992];
    bfu   (*bsHWb)[52] = reinterpret_cast<bfu(*)[52]>(smem);
    bfu*  Pl           = reinterpret_cast<bfu*>(smem + 6656);
    bfu*  Kl           = reinterpret_cast<bfu*>(smem + 10752);
    bfu*  Vl           = reinterpret_cast<bfu*>(smem + 14848);
    float (*bsT)[8]    = reinterpret_cast<float(*)[8]>(smem + 18944);
    bfu   (*Rlb)[68]   = reinterpret_cast<bfu(*)[68]>(smem);
    float (*bsD)[14]   = reinterpret_cast<float(*)[14]>(smem + 10752);

    int t = threadIdx.x;
    int l = t & 63, w = t >> 6;
    int g = l >> 4, r = l & 15;
    int blk = blockIdx.x;
    int qt = blk % 25, bh = blk / 25;
    int h = bh % NHEADS, b = bh / NHEADS;
    int rowbase = qt * 64;
    int qw = rowbase + w * 16;
    int qwc = (qw < NQ) ? qw : (NQ - 16);

    for (int id = t; id < 69 * 64; id += 256) {
        int j = id >> 6, c = id & 63;
        const void* R; int row, rfl;
        if (j < 15)      { R = rpt; row = j;      rfl = ft; }
        else if (j < 42) { R = rph; row = j - 15; rfl = fh; }
        else             { R = rpw; row = j - 42; rfl = fwF; }
        Rlb[j][c] = f2b(ldf(R, (size_t)row * HD + c, rfl));
    }
    int rr = t >> 2, sub = t & 3;
    int nqr = rowbase + rr;
    int nqc = (nqr < NQ) ? nqr : (NQ - 1);
    float qv16[16];
    {
        const bfu* qrow = qb + (size_t)(b * NQ + nqc) * qs + h * HD + sub * 16;
        #pragma unroll
        for (int c4 = 0; c4 < 4; ++c4) {
            ushort4 u = *(const ushort4*)(qrow + c4 * 4);
            qv16[c4 * 4 + 0] = b2f(u.x);
            qv16[c4 * 4 + 1] = b2f(u.y);
            qv16[c4 * 4 + 2] = b2f(u.z);
            qv16[c4 * 4 + 3] = b2f(u.w);
        }
    }
    __syncthreads();

    {
        int tq = nqc / 196, hq = (nqc % 196) / 14, wq = nqc % 14;
        #pragma unroll
        for (int idx = 0; idx < 22; ++idx) {
            int j;
            if (idx < 8)       j = tq - idx + 7;
            else if (idx < 15) j = 15 + hq - 2 * (idx - 8) + 12;
            else               j = 42 + wq - 2 * (idx - 15) + 12;
            float part = 0.f;
            #pragma unroll
            for (int c4 = 0; c4 < 4; ++c4) {
                ushort4 u = *(const ushort4*)&Rlb[j][sub * 16 + c4 * 4];
                part += qv16[c4 * 4 + 0] * b2f(u.x) + qv16[c4 * 4 + 1] * b2f(u.y)
                      + qv16[c4 * 4 + 2] * b2f(u.z) + qv16[c4 * 4 + 3] * b2f(u.w);
            }
            part += __shfl_xor(part, 1);
            part += __shfl_xor(part, 2);
            if (sub == 0) {
                if (idx < 8) bsT[rr][idx] = part - 8.0f;
                else         bsD[rr][idx - 8] = part;
            }
        }
    }
    __syncthreads();

    for (int id = t; id < 64 * 49; id += 256) {
        int rrj = id / 49, r2 = id - rrj * 49;
        bsHWb[rrj][r2] = f2b(bsD[rrj][r2 / 7] + bsD[rrj][7 + r2 % 7]);
    }

    size_t qgrow = (size_t)(b * NQ + qwc + r) * qs + h * HD;
    bf16x8 aq0 = *(const bf16x8*)(qb + qgrow + g * 8);
    bf16x8 aq1 = *(const bf16x8*)(qb + qgrow + 32 + g * 8);

    f32x4 o0, o1, o2, o3;
    #pragma unroll
    for (int i = 0; i < 4; ++i) { o0[i] = 0.f; o1[i] = 0.f; o2[i] = 0.f; o3[i] = 0.f; }
    float lrp[4] = {0.f, 0.f, 0.f, 0.f};

    const bfu* kbase = kp + (size_t)bh * NKV * HD;
    const bfu* vbase = vt + (size_t)bh * HD * NKV;
    f32x4 zero;
    #pragma unroll
    for (int i = 0; i < 4; ++i) zero[i] = 0.f;

    const bfu* ksrc0 = kbase + (size_t)((t >> 7) * 16 + (t & 15)) * HD + ((t >> 4) & 7) * 8;
    const bfu* vsrc0 = vbase + (size_t)((t >> 6) * 16 + (t & 15)) * NKV + ((t >> 4) & 3) * 8;
    int lslot = t * 8;

    int myrow = w * 512 + ((r >> 3) * 16) * 8 + (r & 7);
    int myrow1 = w * 512 + ((2 + (r >> 3)) * 16) * 8 + (r & 7);

    for (int kt0 = 0; kt0 < NKV; kt0 += 32) {
        __syncthreads();
        *(bf16x8*)&Kl[lslot] = *(const bf16x8*)(ksrc0 + (size_t)kt0 * HD);
        *(bf16x8*)&Vl[lslot] = *(const bf16x8*)(vsrc0 + kt0);
        __syncthreads();

        f32x4 s0 = zero, s1 = zero;
        {
            int sl = (g * 16 + r) * 8;
            bf16x8 kf;
            kf = *(const bf16x8*)&Kl[sl];
            s0 = __builtin_amdgcn_mfma_f32_16x16x32_bf16(aq0, kf, s0, 0, 0, 0);
            kf = *(const bf16x8*)&Kl[512 + sl];
            s0 = __builtin_amdgcn_mfma_f32_16x16x32_bf16(aq1, kf, s0, 0, 0, 0);
            kf = *(const bf16x8*)&Kl[1024 + sl];
            s1 = __builtin_amdgcn_mfma_f32_16x16x32_bf16(aq0, kf, s1, 0, 0, 0);
            kf = *(const bf16x8*)&Kl[1536 + sl];
            s1 = __builtin_amdgcn_mfma_f32_16x16x32_bf16(aq1, kf, s1, 0, 0, 0);
        }
        int kj0 = kt0 + r, kj1 = kt0 + 16 + r;
        bool msk0 = (kj0 >= NKV);
        bool msk1 = (kj1 >= NKV);
        int kj0c = msk0 ? (NKV - 1) : kj0;
        int kj1c = msk1 ? (NKV - 1) : kj1;
        int kt_0 = kj0c / 49, r2_0 = kj0c - kt_0 * 49;
        int kt_1 = kj1c / 49, r2_1 = kj1c - kt_1 * 49;
        #pragma unroll
        for (int i = 0; i < 4; ++i) {
            int br = w * 16 + 4 * g + i;
            float v0 = s0[i] * 0.125f + bsT[br][kt_0] + b2f(bsHWb[br][r2_0]);
            float v1 = s1[i] * 0.125f + bsT[br][kt_1] + b2f(bsHWb[br][r2_1]);
            float p0 = msk0 ? 0.f : __expf(v0);
            float p1 = msk1 ? 0.f : __expf(v1);
            lrp[i] += p0 + p1;
            s0[i] = p0; s1[i] = p1;
        }
        #pragma unroll
        for (int i = 0; i < 4; ++i) {
            Pl[myrow + (4 * g + i) * 8]  = f2b(s0[i]);
            Pl[myrow1 + (4 * g + i) * 8] = f2b(s1[i]);
        }
        bf16x8 pf = *(const bf16x8*)&Pl[w * 512 + (g * 16 + r) * 8];
        int vsl = (g * 16 + r) * 8;
        bf16x8 vf;
        vf = *(const bf16x8*)&Vl[vsl];
        o0 = __builtin_amdgcn_mfma_f32_16x16x32_bf16(pf, vf, o0, 0, 0, 0);
        vf = *(const bf16x8*)&Vl[512 + vsl];
        o1 = __builtin_amdgcn_mfma_f32_16x16x32_bf16(pf, vf, o1, 0, 0, 0);
        vf = *(const bf16x8*)&Vl[1024 + vsl];
        o2 = __builtin_amdgcn_mfma_f32_16x16x32_bf16(pf, vf, o2, 0, 0, 0);
        vf = *(const bf16x8*)&Vl[1536 + vsl];
        o3 = __builtin_amdgcn_mfma_f32_16x16x32_bf16(pf, vf, o3, 0, 0, 0);
    }

    if (qw < NQ) {
        #pragma unroll
        for (int i = 0; i < 4; ++i) {
            float lsum = lrp[i];
            lsum += __shfl_xor(lsum, 1);
            lsum += __shfl_xor(lsum, 2);
            lsum += __shfl_xor(lsum, 4);
            lsum += __shfl_xor(lsum, 8);
            float inv = 1.f / lsum;
            size_t rix = (size_t)(b * NQ + qw + 4 * g + i);
            size_t qres = rix * qs + h * HD + r;
            size_t orow = rix * DIM + h * HD + r;
            ao[orow]      = f2b(o0[i] * inv + b2f(qb[qres]));
            ao[orow + 16] = f2b(o1[i] * inv + b2f(qb[qres + 16]));
            ao[orow + 32] = f2b(o2[i] * inv + b2f(qb[qres + 32]));
            ao[orow + 48] = f2b(o3[i] * inv + b2f(qb[qres + 48]));
        }
    }
}

extern "C" void kernel_launch(void* const* d_in, const int* in_sizes, int n_in,
                              void* d_out, int out_size, void* d_ws, size_t ws_size,
                              hipStream_t stream) {
    Ptrs ptrs;
    for (int i = 0; i < 16; ++i) ptrs.p[i] = d_in[i];
    const void* x      = d_in[0];
    const void* ln_w   = d_in[1];
    const void* ln_b   = d_in[2];
    const void* qkv_w  = d_in[3];
    const void* qkv_b  = d_in[4];
    const void* proj_w = d_in[5];
    const void* proj_b = d_in[6];
    const void* poolk_w = d_in[7];
    const void* poolv_w = d_in[8];
    const void* rph    = d_in[13];
    const void* rpw    = d_in[14];
    const void* rpt    = d_in[15];

    bfu* ws = (bfu*)d_ws;
    float* out = (float*)d_out;

    // all-ws layout (38.44 MB; ws >= 43.35 MB confirmed by round-27 branch):
    bfu* A      = ws;                     //  4,816,896: xn, later attention out
    bfu* Bf     = ws + 4816896;           //  4,816,896: v-slice, then q-slice
    bfu* kslice = ws + 9633792;           //  4,816,896: k projection
    bfu* kp     = ws + 14450688;          //  1,204,224: K [bh][kj][d]
    bfu* vt     = ws + 15654912;          //  1,204,224: V^T [bh][d][kj]
    bfu* WTq    = ws + 16859136;          //  1,769,472: qkv W^T bf16
    bfu* WTp    = ws + 18628608;          //    589,824: proj W^T bf16
    int* flags  = (int*)(ws + 19218432);  //  64 bytes

    probe_kernel<<<16, 64, 0, stream>>>(ptrs, flags);

    // merged: LN(x) -> A  +  qkv_w -> WTq  +  proj_w -> WTp
    ln_wcvt_kernel<<<6848, 256, 0, stream>>>(x, ln_w, ln_b, A, qkv_w, WTq,
                                             proj_w, WTp, flags);

    // fused k+v GEMM: N=1536 (WT rows 768..2303); k -> kslice, v -> Bf
    gemm_mfma_kernel<false><<<98 * 24, 64, 0, stream>>>(
        A, WTq + (size_t)DIM * 768, qkv_b, kslice, Bf, DIM, DIM, 24, 768, flags, 4);

    // full-row pools: K (kslice -> kp) + V (Bf -> vt)
    pool3_kernel<<<2 * BATCH * NKV, 256, 0, stream>>>(
        kslice, Bf, poolk_w, poolv_w,
        d_in[9], d_in[10], d_in[11], d_in[12], kp, vt, 768, flags);

    // q GEMM (WT rows 0..767) -> Bf (v dead after pool)
    gemm_mfma_kernel<false><<<98 * 12, 64, 0, stream>>>(
        A, WTq, qkv_b, Bf, nullptr, 0, 1 << 30, 12, 768, flags, 4);

    attn_mfma_kernel<<<48 * 25, 256, 0, stream>>>(
        Bf, kp, vt, rpt, rph, rpw, A, 768, flags);

    // proj GEMM (WTp precomputed in first kernel)
    gemm_mfma_kernel<true><<<98 * 12, 64, 0, stream>>>(
        A, WTp, proj_b, out, nullptr, 0, 1 << 30, 12, 768, flags, 6);
}